// Round 9
// baseline (397.750 us; speedup 1.0000x reference)
//
#include <hip/hip_runtime.h>

// ---------- types ----------
typedef __attribute__((ext_vector_type(8))) short  s8v;    // 8 bf16 (as shorts) = 4 VGPR
typedef __attribute__((ext_vector_type(8))) unsigned short us8;
typedef __attribute__((ext_vector_type(4))) float  f4v;    // MFMA accumulator

// float -> bf16 round-to-nearest-even (inputs are finite)
__device__ __forceinline__ unsigned short f2bf(float f) {
  unsigned int u = __builtin_bit_cast(unsigned int, f);
  u += 0x7fffu + ((u >> 16) & 1u);
  return (unsigned short)(u >> 16);
}

// async global->LDS, 16B per lane; offset arg must stay 0 (only verified mode).
__device__ __forceinline__ void gll16(const void* g, void* l) {
  __builtin_amdgcn_global_load_lds(
      (const __attribute__((address_space(1))) unsigned int*)g,
      (__attribute__((address_space(3))) unsigned int*)l, 16, 0, 0);
}

// ---------- kernel 1: x fp32 -> bf16 ----------
__global__ __launch_bounds__(256) void cast_bf16(const float* __restrict__ in,
                                                 unsigned short* __restrict__ out) {
  const size_t i = (size_t)blockIdx.x * 256 + threadIdx.x;
  const f4v* p = (const f4v*)in;
  f4v a = p[2 * i];
  f4v b = p[2 * i + 1];
  us8 r;
  r[0] = f2bf(a[0]); r[1] = f2bf(a[1]); r[2] = f2bf(a[2]); r[3] = f2bf(a[3]);
  r[4] = f2bf(b[0]); r[5] = f2bf(b[1]); r[6] = f2bf(b[2]); r[7] = f2bf(b[3]);
  *(us8*)&out[i * 8] = r;
}

// ---------- kernel 2: T[o1,i1,o2,i2,r2] = sum_r1 core0*core1 ----------
__global__ __launch_bounds__(256) void contract1(const float* __restrict__ c0,
                                                 const float* __restrict__ c1,
                                                 float* __restrict__ T) {
  const int idx = blockIdx.x * 256 + threadIdx.x;
  const int r2  = idx & 63;
  const int oi2 = (idx >> 6) & 255;
  const int oi1 = idx >> 14;
  const float* c0p = c0 + oi1 * 64;
  const float* c1p = c1 + oi2 * 64 + r2;
  float s = 0.f;
#pragma unroll 8
  for (int r1 = 0; r1 < 64; ++r1)
    s = fmaf(c0p[r1], c1p[r1 * 16384], s);
  T[idx] = s;
}

// ---------- kernel 3: W build, LDS-staged ----------
__global__ __launch_bounds__(1024) void buildW2(const float* __restrict__ T,
                                                const float* __restrict__ c2,
                                                unsigned short* __restrict__ W) {
  __shared__ float c2s[16384];      // 64 KB: [r2][o3][i3]
  __shared__ float Tl[16640];       // 65 KB: [ii][r2], stride 65

  const int tid = threadIdx.x;
  const int o1  = blockIdx.x >> 4;
  const int o2  = blockIdx.x & 15;

#pragma unroll
  for (int j = 0; j < 4; ++j)
    ((f4v*)c2s)[j * 1024 + tid] = ((const f4v*)c2)[j * 1024 + tid];

#pragma unroll
  for (int rr = 0; rr < 4; ++rr) {
    const int i1 = rr * 4 + (tid >> 8);
    const float* src = T + (size_t)(o1 * 16 + i1) * 16384 + o2 * 1024;
    const int c = tid & 255;
    f4v v = ((const f4v*)src)[c];
    float* dst = &Tl[(i1 * 16 + (c >> 4)) * 65 + (c & 15) * 4];
    dst[0] = v[0]; dst[1] = v[1]; dst[2] = v[2]; dst[3] = v[3];
  }
  __syncthreads();

  const int ii = tid & 255;
  const int i1 = ii >> 4, i2 = ii & 15;
#pragma unroll
  for (int k = 0; k < 4; ++k) {
    const int o3 = k * 4 + (tid >> 8);
    float acc[16];
#pragma unroll
    for (int j = 0; j < 16; ++j) acc[j] = 0.f;
    for (int r2 = 0; r2 < 64; ++r2) {
      const float t = Tl[ii * 65 + r2];
      const f4v* cp = (const f4v*)&c2s[r2 * 256 + o3 * 16];
      f4v c0q = cp[0], c1q = cp[1], c2q = cp[2], c3q = cp[3];
#pragma unroll
      for (int j = 0; j < 4; ++j) acc[j]      = fmaf(t, c0q[j], acc[j]);
#pragma unroll
      for (int j = 0; j < 4; ++j) acc[4 + j]  = fmaf(t, c1q[j], acc[4 + j]);
#pragma unroll
      for (int j = 0; j < 4; ++j) acc[8 + j]  = fmaf(t, c2q[j], acc[8 + j]);
#pragma unroll
      for (int j = 0; j < 4; ++j) acc[12 + j] = fmaf(t, c3q[j], acc[12 + j]);
    }
    us8 w0, w1;
#pragma unroll
    for (int j = 0; j < 8; ++j) { w0[j] = f2bf(acc[j]); w1[j] = f2bf(acc[8 + j]); }
    unsigned short* dst =
        &W[(size_t)(o1 * 256 + o2 * 16 + o3) * 4096 + i1 * 256 + i2 * 16];
    *(us8*)dst = w0;
    *((us8*)(dst + 8)) = w1;
  }
}

// ---------- kernel 4: 256x256-tile 8-phase GEMM, C = A * B^T ----------
// A[M][K], B[N][K] bf16, C[M][N] fp32. M=8192, N=4096, K=4096.
// LDS (ushort idx): A: buf*16384 + kh*8192 + row*32 + slot*8 ; B: +32768.
// Swizzle: 16B-slot ^= (row>>1)&3 on read; inverse on global source (rule #21).
// Staging schedule (R8): burst-stage t+1's kh0 (A+B) at P0 and kh1 (A+B) at P1;
// guards VMW(4) at P0-end (drains kh1(cur), 3-phase flight) and P2-end (drains
// kh0(t+1), 2-phase flight). Min flight 2 phases ~1200cy > HBM ~900cy — no
// exposed load latency (R7's VMW(2) schedule gave only 1 phase ~600cy).

#define BAR() __builtin_amdgcn_s_barrier()
#define VMW(N) asm volatile("s_waitcnt vmcnt(" #N ")" ::: "memory")

template<int MH>
__device__ __forceinline__ void mm16(f4v (&acc)[8][4], const s8v (&aF)[4], const s8v (&bF)[4]) {
  __builtin_amdgcn_s_setprio(1);
#pragma unroll
  for (int m = 0; m < 4; ++m)
#pragma unroll
    for (int n = 0; n < 4; ++n)
      acc[MH * 4 + m][n] =
          __builtin_amdgcn_mfma_f32_16x16x32_bf16(aF[m], bF[n], acc[MH * 4 + m][n], 0, 0, 0);
  __builtin_amdgcn_s_setprio(0);
}

__global__ __launch_bounds__(512, 2) void gemm8(const unsigned short* __restrict__ A,
                                                const unsigned short* __restrict__ B,
                                                float* __restrict__ C) {
  constexpr int M = 8192, N = 4096, K = 4096;
  constexpr int NT = K / 64;      // 64 K-tiles
  constexpr int NXT = N / 256;    // 16 tiles in N

  __shared__ unsigned short lds[65536];   // 128 KiB

  const int tid  = threadIdx.x;
  const int lane = tid & 63;
  const int wid  = tid >> 6;      // 0..7
  const int wm   = wid >> 2;      // 0..1
  const int wn   = wid & 3;       // 0..3

  // XCD-aware bijective swizzle (gridDim.x = 512, divisible by 8)
  const int cpx = (int)gridDim.x >> 3;
  const int wg  = ((int)blockIdx.x & 7) * cpx + ((int)blockIdx.x >> 3);
  const long bm = (long)(wg / NXT) * 256;
  const long bn = (long)(wg % NXT) * 256;

  // ---- staging addressing (incremented pointers) ----
  const int r0  = tid >> 2;
  const int sx0 = (tid & 3) ^ ((r0 >> 1) & 3);    // inverse-swizzled global 16B slot
  const unsigned short* gA  = A + (bm + r0) * (size_t)K + sx0 * 8;
  const unsigned short* gA2 = gA + 128 * (size_t)K;
  const unsigned short* gB  = B + (bn + r0) * (size_t)K + sx0 * 8;
  const unsigned short* gB2 = gB + 128 * (size_t)K;
  const int ldst = tid * 8;                        // linear LDS dest (ushorts)

#define STAGE(isB, KH, dstU) do {                                                \
    const unsigned short* gl_ = (isB ? gB : gA) + (KH) * 32;                     \
    const unsigned short* gh_ = (isB ? gB2 : gA2) + (KH) * 32;                   \
    unsigned short* l_ = &lds[(isB ? 32768 : 0) + (dstU) + (KH) * 8192 + ldst];  \
    gll16(gl_, l_);                                                              \
    gll16(gh_, l_ + 4096);                                                       \
  } while (0)

  // ---- fragment read addressing ----
  const int fr = lane & 15;
  const int ks = lane >> 4;                       // 0..3 (16B k-slot)
  const int swz = (ks ^ ((fr >> 1) & 3)) << 3;    // swizzled slot, ushort units
  const int aoff = (wm * 128 + fr) * 32 + swz;
  const int boff = (wn * 64 + fr) * 32 + swz;

#define RDA(dst, kh, bufU, mh) do {                                              \
    const unsigned short* p_ = &lds[(bufU) + (kh) * 8192 + aoff + (mh) * 2048];  \
    dst[0] = *(const s8v*)(p_);        dst[1] = *(const s8v*)(p_ + 512);         \
    dst[2] = *(const s8v*)(p_ + 1024); dst[3] = *(const s8v*)(p_ + 1536);        \
  } while (0)
#define RDB(dst, kh, bufU) do {                                                  \
    const unsigned short* p_ = &lds[32768 + (bufU) + (kh) * 8192 + boff];        \
    dst[0] = *(const s8v*)(p_);        dst[1] = *(const s8v*)(p_ + 512);         \
    dst[2] = *(const s8v*)(p_ + 1024); dst[3] = *(const s8v*)(p_ + 1536);        \
  } while (0)

  f4v acc[8][4];
#pragma unroll
  for (int m = 0; m < 8; ++m)
#pragma unroll
    for (int n = 0; n < 4; ++n) acc[m][n] = (f4v)0.0f;

  // prologue: stage K-tile 0 into buf 0 (A-kh0, B-kh0, A-kh1, B-kh1)
  STAGE(0, 0, 0);
  STAGE(1, 0, 0);
  STAGE(0, 1, 0);
  STAGE(1, 1, 0);
  VMW(4);          // kh0 A+B landed; kh1 pair may fly
  BAR();
  gA += 64; gA2 += 64; gB += 64; gB2 += 64;   // now point at K-tile 1

  s8v aP[4], aQ[4], bP[4], bQ[4];
  int curU = 0;
  RDA(aP, 0, 0, 0);            // F0: A(mh0,kh0)
  RDB(bP, 0, 0);               //     B(kh0)

  for (int t = 0; t < NT; ++t) {
    const int nxtU = curU ^ 16384;
    // ---- P0: MFMA F0(aP,bP); read F1; stage kh0(t+1) A+B ----
    RDA(aQ, 0, curU, 1);
    STAGE(0, 0, nxtU); STAGE(1, 0, nxtU);
    BAR(); mm16<0>(acc, aP, bP);
    VMW(4);        // drains kh1(cur) A+B (issued 3 phases ago); kh0(t+1) flies
    BAR();
    // ---- P1: MFMA F1(aQ,bP); read F2; stage kh1(t+1) A+B ----
    RDA(aP, 1, curU, 0); RDB(bQ, 1, curU);
    STAGE(0, 1, nxtU); STAGE(1, 1, nxtU);
    BAR(); mm16<1>(acc, aQ, bP); BAR();
    // ---- P2: MFMA F2(aP,bQ); read F3 ----
    RDA(aQ, 1, curU, 1);
    BAR(); mm16<0>(acc, aP, bQ);
    VMW(4);        // drains kh0(t+1) A+B (issued 2 phases ago); kh1(t+1) flies
    BAR();
    // ---- P3: MFMA F3(aQ,bQ); read F0 of next tile ----
    RDA(aP, 0, nxtU, 0); RDB(bP, 0, nxtU);
    BAR(); mm16<1>(acc, aQ, bQ); BAR();
    // advance pointers; wrap before the last tile's dummy prefetch (stays in-bounds)
    const long d = (t == NT - 2) ? -(long)((NT - 1) * 64) : 64;
    gA += d; gA2 += d; gB += d; gB2 += d;
    curU = nxtU;
  }
  VMW(0);          // drain dummy prefetch before retire

  // ---- epilogue: C/D layout col = lane&15, row = (lane>>4)*4 + r ----
  const long crow0 = bm + wm * 128 + ks * 4;
  const long ccol0 = bn + wn * 64 + fr;
#pragma unroll
  for (int mf = 0; mf < 8; ++mf)
#pragma unroll
    for (int n = 0; n < 4; ++n)
#pragma unroll
      for (int r = 0; r < 4; ++r)
        C[(size_t)(crow0 + mf * 16 + r) * N + ccol0 + n * 16] = acc[mf][n][r];
#undef STAGE
#undef RDA
#undef RDB
}

// ---------- launch ----------
extern "C" void kernel_launch(void* const* d_in, const int* in_sizes, int n_in,
                              void* d_out, int out_size, void* d_ws, size_t ws_size,
                              hipStream_t stream) {
  const float* x  = (const float*)d_in[0];   // [8192,4096]
  const float* c0 = (const float*)d_in[1];   // [1,16,16,64]
  const float* c1 = (const float*)d_in[2];   // [64,16,16,64]
  const float* c2 = (const float*)d_in[3];   // [64,16,16,1]
  float* out = (float*)d_out;                // [8192,4096] fp32

  char* ws = (char*)d_ws;
  float*          T  = (float*)ws;                              // 16 MB
  unsigned short* Wb = (unsigned short*)(ws + (16u << 20));     // 32 MB  [out=4096][in=4096] bf16
  unsigned short* xb = (unsigned short*)(ws + (48u << 20));     // 64 MB  [8192][4096] bf16

  hipLaunchKernelGGL(cast_bf16, dim3(16384), dim3(256), 0, stream, x, xb);
  hipLaunchKernelGGL(contract1, dim3(16384), dim3(256), 0, stream, c0, c1, T);
  hipLaunchKernelGGL(buildW2,   dim3(256),   dim3(1024), 0, stream, T, c2, Wb);
  hipLaunchKernelGGL(gemm8,     dim3(512),   dim3(512), 0, stream, xb, Wb, out);
}

// Round 10
// 361.421 us; speedup vs baseline: 1.1005x; 1.1005x over previous
//
#include <hip/hip_runtime.h>

// ---------- types ----------
typedef __attribute__((ext_vector_type(8))) short  s8v;    // 8 bf16 (as shorts) = 4 VGPR
typedef __attribute__((ext_vector_type(8))) unsigned short us8;
typedef __attribute__((ext_vector_type(4))) float  f4v;    // MFMA accumulator

// float -> bf16 round-to-nearest-even (inputs are finite)
__device__ __forceinline__ unsigned short f2bf(float f) {
  unsigned int u = __builtin_bit_cast(unsigned int, f);
  u += 0x7fffu + ((u >> 16) & 1u);
  return (unsigned short)(u >> 16);
}

// async global->LDS, 16B per lane; offset arg must stay 0 (only verified mode).
__device__ __forceinline__ void gll16(const void* g, void* l) {
  __builtin_amdgcn_global_load_lds(
      (const __attribute__((address_space(1))) unsigned int*)g,
      (__attribute__((address_space(3))) unsigned int*)l, 16, 0, 0);
}

// ---------- kernel 1: x fp32 -> bf16 ----------
__global__ __launch_bounds__(256) void cast_bf16(const float* __restrict__ in,
                                                 unsigned short* __restrict__ out) {
  const size_t i = (size_t)blockIdx.x * 256 + threadIdx.x;
  const f4v* p = (const f4v*)in;
  f4v a = p[2 * i];
  f4v b = p[2 * i + 1];
  us8 r;
  r[0] = f2bf(a[0]); r[1] = f2bf(a[1]); r[2] = f2bf(a[2]); r[3] = f2bf(a[3]);
  r[4] = f2bf(b[0]); r[5] = f2bf(b[1]); r[6] = f2bf(b[2]); r[7] = f2bf(b[3]);
  *(us8*)&out[i * 8] = r;
}

// ---------- kernel 2: T[o1,i1,o2,i2,r2] = sum_r1 core0*core1 ----------
__global__ __launch_bounds__(256) void contract1(const float* __restrict__ c0,
                                                 const float* __restrict__ c1,
                                                 float* __restrict__ T) {
  const int idx = blockIdx.x * 256 + threadIdx.x;
  const int r2  = idx & 63;
  const int oi2 = (idx >> 6) & 255;
  const int oi1 = idx >> 14;
  const float* c0p = c0 + oi1 * 64;
  const float* c1p = c1 + oi2 * 64 + r2;
  float s = 0.f;
#pragma unroll 8
  for (int r1 = 0; r1 < 64; ++r1)
    s = fmaf(c0p[r1], c1p[r1 * 16384], s);
  T[idx] = s;
}

// ---------- kernel 3: W build, LDS-staged ----------
__global__ __launch_bounds__(1024) void buildW2(const float* __restrict__ T,
                                                const float* __restrict__ c2,
                                                unsigned short* __restrict__ W) {
  __shared__ float c2s[16384];      // 64 KB: [r2][o3][i3]
  __shared__ float Tl[16640];       // 65 KB: [ii][r2], stride 65

  const int tid = threadIdx.x;
  const int o1  = blockIdx.x >> 4;
  const int o2  = blockIdx.x & 15;

#pragma unroll
  for (int j = 0; j < 4; ++j)
    ((f4v*)c2s)[j * 1024 + tid] = ((const f4v*)c2)[j * 1024 + tid];

#pragma unroll
  for (int rr = 0; rr < 4; ++rr) {
    const int i1 = rr * 4 + (tid >> 8);
    const float* src = T + (size_t)(o1 * 16 + i1) * 16384 + o2 * 1024;
    const int c = tid & 255;
    f4v v = ((const f4v*)src)[c];
    float* dst = &Tl[(i1 * 16 + (c >> 4)) * 65 + (c & 15) * 4];
    dst[0] = v[0]; dst[1] = v[1]; dst[2] = v[2]; dst[3] = v[3];
  }
  __syncthreads();

  const int ii = tid & 255;
  const int i1 = ii >> 4, i2 = ii & 15;
#pragma unroll
  for (int k = 0; k < 4; ++k) {
    const int o3 = k * 4 + (tid >> 8);
    float acc[16];
#pragma unroll
    for (int j = 0; j < 16; ++j) acc[j] = 0.f;
    for (int r2 = 0; r2 < 64; ++r2) {
      const float t = Tl[ii * 65 + r2];
      const f4v* cp = (const f4v*)&c2s[r2 * 256 + o3 * 16];
      f4v c0q = cp[0], c1q = cp[1], c2q = cp[2], c3q = cp[3];
#pragma unroll
      for (int j = 0; j < 4; ++j) acc[j]      = fmaf(t, c0q[j], acc[j]);
#pragma unroll
      for (int j = 0; j < 4; ++j) acc[4 + j]  = fmaf(t, c1q[j], acc[4 + j]);
#pragma unroll
      for (int j = 0; j < 4; ++j) acc[8 + j]  = fmaf(t, c2q[j], acc[8 + j]);
#pragma unroll
      for (int j = 0; j < 4; ++j) acc[12 + j] = fmaf(t, c2q[j] * 0.f + ((const f4v*)&c2s[r2 * 256 + o3 * 16])[3][j], acc[12 + j]);
    }
    us8 w0, w1;
#pragma unroll
    for (int j = 0; j < 8; ++j) { w0[j] = f2bf(acc[j]); w1[j] = f2bf(acc[8 + j]); }
    unsigned short* dst =
        &W[(size_t)(o1 * 256 + o2 * 16 + o3) * 4096 + i1 * 256 + i2 * 16];
    *(us8*)dst = w0;
    *((us8*)(dst + 8)) = w1;
  }
}

// ---------- kernel 4: 256x256-tile GEMM, m201-style 8-phase / 2 K-tiles per iter ----------
// A[M][K], B[N][K] bf16, C[M][N] fp32. M=8192, N=4096, K=4096.
// LDS: 2 bufs x {A-lo, A-hi, B-lo, B-hi} half-tiles, each 128 rows x 64 cols (16KB).
// Row = 128B (all 32 banks); 16B-slot swizzle: slot ^= row&7 (write-source & read).
// Wave output 128x64 SPLIT across halves: rows wm*64+mq*128, cols wn*32+nq*128.
// Phases per K-tile: P1=Q(0,0) reads A-lo+B-lo(12); P2=Q(0,1) reads B-hi(4);
// P3=Q(1,1) reads A-hi(8); P4=Q(1,0) reads 0 (B-lo regs live). Each phase stages
// exactly one half-tile into a region dead by schedule; VMW(4) only at P4/P8.

#define BAR() __builtin_amdgcn_s_barrier()
#define VMW(N) asm volatile("s_waitcnt vmcnt(" #N ")" ::: "memory")

template<int MQ, int NQ>
__device__ __forceinline__ void mmq(f4v (&acc)[8][4], const s8v (&a)[4][2], const s8v (&b)[2][2]) {
  __builtin_amdgcn_s_setprio(1);
#pragma unroll
  for (int mi = 0; mi < 4; ++mi)
#pragma unroll
    for (int ni = 0; ni < 2; ++ni)
#pragma unroll
      for (int q = 0; q < 2; ++q)
        acc[MQ * 4 + mi][NQ * 2 + ni] = __builtin_amdgcn_mfma_f32_16x16x32_bf16(
            a[mi][q], b[ni][q], acc[MQ * 4 + mi][NQ * 2 + ni], 0, 0, 0);
  __builtin_amdgcn_s_setprio(0);
}

__global__ __launch_bounds__(512, 2) void gemm8(const unsigned short* __restrict__ A,
                                                const unsigned short* __restrict__ B,
                                                float* __restrict__ C) {
  constexpr int M = 8192, N = 4096, K = 4096;
  constexpr int NT = K / 64;        // 64 K-tiles
  constexpr int NITER = NT / 2;     // 32 iters, 2 K-tiles each
  constexpr int NXT = N / 256;

  __shared__ unsigned short lds[65536];   // 128 KiB: buf0 @0, buf1 @32768 (ushorts)

  const int tid  = threadIdx.x;
  const int lane = tid & 63;
  const int wid  = tid >> 6;
  const int wm   = wid >> 2;        // 0..1
  const int wn   = wid & 3;         // 0..3

  const int cpx = (int)gridDim.x >> 3;
  const int wg  = ((int)blockIdx.x & 7) * cpx + ((int)blockIdx.x >> 3);
  const long bm = (long)(wg / NXT) * 256;
  const long bn = (long)(wg % NXT) * 256;

  // ---- staging addressing: thread t -> row=t>>3 (0..63), slot=t&7; source col
  // pre-swizzled (slot ^ row&7); call2 = +64 rows (same swizzle: row&7 equal).
  const int srow = tid >> 3;
  const int scol = ((tid & 7) ^ (srow & 7)) * 8;
  const unsigned short* gA = A + (bm + srow) * (size_t)K + scol;
  const unsigned short* gB = B + (bn + srow) * (size_t)K + scol;
  const size_t half64 = 64 * (size_t)K;
  const size_t k128   = 128 * (size_t)K;

  // STG one half-tile (128 rows x 64 cols = 16KB): 2 gll16/thread, linear dests.
#define STG(gp, koff, ldsU) do {                                  \
    const unsigned short* g_ = (gp) + (koff);                     \
    gll16(g_,          &lds[(ldsU) + tid * 8]);                   \
    gll16(g_ + half64, &lds[(ldsU) + 4096 + tid * 8]);            \
  } while (0)

  // ---- fragment read addressing ----
  const int fr = lane & 15;
  const int ks = lane >> 4;                 // 0..3
  const int f7 = fr & 7;
  const int sx0 = (ks ^ f7) * 8;            // k-step q=0 slot (ushorts)
  const int sx1 = ((ks | 4) ^ f7) * 8;      // q=1
  const int arow = (wm * 64 + fr) * 64;     // within A half-region (8192 ushorts)
  const int brow = (wn * 32 + fr) * 64;     // within B half-region

#define RDA(MQ, bufU) do {                                                   \
    const unsigned short* p_ = &lds[(bufU) + (MQ) * 8192 + arow];            \
    a[0][0] = *(const s8v*)(p_ + sx0);        a[0][1] = *(const s8v*)(p_ + sx1); \
    a[1][0] = *(const s8v*)(p_ + 1024 + sx0); a[1][1] = *(const s8v*)(p_ + 1024 + sx1); \
    a[2][0] = *(const s8v*)(p_ + 2048 + sx0); a[2][1] = *(const s8v*)(p_ + 2048 + sx1); \
    a[3][0] = *(const s8v*)(p_ + 3072 + sx0); a[3][1] = *(const s8v*)(p_ + 3072 + sx1); \
  } while (0)
#define RDB(dst, NQ, bufU) do {                                              \
    const unsigned short* p_ = &lds[(bufU) + 16384 + (NQ) * 8192 + brow];    \
    dst[0][0] = *(const s8v*)(p_ + sx0);        dst[0][1] = *(const s8v*)(p_ + sx1); \
    dst[1][0] = *(const s8v*)(p_ + 1024 + sx0); dst[1][1] = *(const s8v*)(p_ + 1024 + sx1); \
  } while (0)

  f4v acc[8][4];
#pragma unroll
  for (int m = 0; m < 8; ++m)
#pragma unroll
    for (int n = 0; n < 4; ++n) acc[m][n] = (f4v)0.0f;

  // prologue: tile0 (all 4 halves, buf0), tile1 (A-lo, B-hi, buf1)
  STG(gA,        0, 0);              // A-lo(t0)
  STG(gA + k128, 0, 8192);           // A-hi(t0)
  STG(gB,        0, 16384);          // B-lo(t0)
  STG(gB + k128, 0, 24576);          // B-hi(t0)
  STG(gA,        64, 32768);         // A-lo(t1)
  STG(gB + k128, 64, 32768 + 24576); // B-hi(t1)
  VMW(4);        // tile0's 8 loads drained; t1's 2 halves fly
  BAR();

  s8v a[4][2], b0[2][2], b1[2][2];

  for (int i = 0; i < NITER; ++i) {
    const long w = (i == NITER - 1) ? -4096L : 0L;   // wrap dummy stages in-bounds
    // ---- P1: Q(0,0) of c0 [buf0]; stage A-hi(c1) ----
    RDA(0, 0); RDB(b0, 0, 0);
    STG(gA + k128, 64, 32768 + 8192);
    BAR(); mmq<0, 0>(acc, a, b0); BAR();
    // ---- P2: Q(0,1); stage B-lo(c1) ----
    RDB(b1, 1, 0);
    STG(gB, 64, 32768 + 16384);
    BAR(); mmq<0, 1>(acc, a, b1); BAR();
    // ---- P3: Q(1,1); stage A-lo(c0+2) ----
    RDA(1, 0);
    STG(gA, 128 + w, 0);
    BAR(); mmq<1, 1>(acc, a, b1); BAR();
    // ---- P4: Q(1,0); stage B-hi(c0+2); VMW lands ALL of c1 ----
    STG(gB + k128, 128 + w, 24576);
    BAR(); mmq<1, 0>(acc, a, b0);
    VMW(4); BAR();
    // ---- P5: Q(0,0) of c1 [buf1]; stage A-hi(c0+2) ----
    RDA(0, 32768); RDB(b0, 0, 32768);
    STG(gA + k128, 128 + w, 8192);
    BAR(); mmq<0, 0>(acc, a, b0); BAR();
    // ---- P6: Q(0,1); stage B-lo(c0+2) ----
    RDB(b1, 1, 32768);
    STG(gB, 128 + w, 16384);
    BAR(); mmq<0, 1>(acc, a, b1); BAR();
    // ---- P7: Q(1,1); stage A-lo(c1+2) ----
    RDA(1, 32768);
    STG(gA, 192 + w, 32768);
    BAR(); mmq<1, 1>(acc, a, b1); BAR();
    // ---- P8: Q(1,0); stage B-hi(c1+2); VMW lands ALL of c0+2 ----
    STG(gB + k128, 192 + w, 32768 + 24576);
    BAR(); mmq<1, 0>(acc, a, b0);
    VMW(4); BAR();

    gA += 128; gB += 128;
  }
  VMW(0);        // drain last dummy prefetches

  // ---- epilogue: row = bm + mq*128 + wm*64 + mi*16 + ks*4 + r ; col = bn + nq*128 + wn*32 + ni*16 + fr
#pragma unroll
  for (int mq = 0; mq < 2; ++mq)
#pragma unroll
    for (int mi = 0; mi < 4; ++mi)
#pragma unroll
      for (int nq = 0; nq < 2; ++nq)
#pragma unroll
        for (int ni = 0; ni < 2; ++ni) {
          const size_t row0 = bm + mq * 128 + wm * 64 + mi * 16 + ks * 4;
          const size_t col  = bn + nq * 128 + wn * 32 + ni * 16 + fr;
          float* cp = C + row0 * (size_t)N + col;
          f4v v = acc[mq * 4 + mi][nq * 2 + ni];
          cp[0] = v[0]; cp[N] = v[1]; cp[2 * (size_t)N] = v[2]; cp[3 * (size_t)N] = v[3];
        }
#undef STG
#undef RDA
#undef RDB
}

// ---------- launch ----------
extern "C" void kernel_launch(void* const* d_in, const int* in_sizes, int n_in,
                              void* d_out, int out_size, void* d_ws, size_t ws_size,
                              hipStream_t stream) {
  const float* x  = (const float*)d_in[0];   // [8192,4096]
  const float* c0 = (const float*)d_in[1];   // [1,16,16,64]
  const float* c1 = (const float*)d_in[2];   // [64,16,16,64]
  const float* c2 = (const float*)d_in[3];   // [64,16,16,1]
  float* out = (float*)d_out;                // [8192,4096] fp32

  char* ws = (char*)d_ws;
  float*          T  = (float*)ws;                              // 16 MB
  unsigned short* Wb = (unsigned short*)(ws + (16u << 20));     // 32 MB  [out=4096][in=4096] bf16
  unsigned short* xb = (unsigned short*)(ws + (48u << 20));     // 64 MB  [8192][4096] bf16

  hipLaunchKernelGGL(cast_bf16, dim3(16384), dim3(256), 0, stream, x, xb);
  hipLaunchKernelGGL(contract1, dim3(16384), dim3(256), 0, stream, c0, c1, T);
  hipLaunchKernelGGL(buildW2,   dim3(256),   dim3(1024), 0, stream, T, c2, Wb);
  hipLaunchKernelGGL(gemm8,     dim3(512),   dim3(512), 0, stream, xb, Wb, out);
}

// Round 11
// 311.885 us; speedup vs baseline: 1.2753x; 1.1588x over previous
//
#include <hip/hip_runtime.h>

// ---------- types ----------
typedef __attribute__((ext_vector_type(8))) short  s8v;    // 8 bf16 (as shorts) = 4 VGPR
typedef __attribute__((ext_vector_type(8))) unsigned short us8;
typedef __attribute__((ext_vector_type(4))) unsigned short us4;
typedef __attribute__((ext_vector_type(4))) float  f4v;    // MFMA accumulator

// float -> bf16 round-to-nearest-even (inputs are finite)
__device__ __forceinline__ unsigned short f2bf(float f) {
  unsigned int u = __builtin_bit_cast(unsigned int, f);
  u += 0x7fffu + ((u >> 16) & 1u);
  return (unsigned short)(u >> 16);
}

// async global->LDS, 16B per lane; offset arg must stay 0 (only verified mode).
__device__ __forceinline__ void gll16(const void* g, void* l) {
  __builtin_amdgcn_global_load_lds(
      (const __attribute__((address_space(1))) unsigned int*)g,
      (__attribute__((address_space(3))) unsigned int*)l, 16, 0, 0);
}

// ---------- kernel 1: x fp32 -> bf16 ----------
__global__ __launch_bounds__(256) void cast_bf16(const float* __restrict__ in,
                                                 unsigned short* __restrict__ out) {
  const size_t i = (size_t)blockIdx.x * 256 + threadIdx.x;
  const f4v* p = (const f4v*)in;
  f4v a = p[2 * i];
  f4v b = p[2 * i + 1];
  us8 r;
  r[0] = f2bf(a[0]); r[1] = f2bf(a[1]); r[2] = f2bf(a[2]); r[3] = f2bf(a[3]);
  r[4] = f2bf(b[0]); r[5] = f2bf(b[1]); r[6] = f2bf(b[2]); r[7] = f2bf(b[3]);
  *(us8*)&out[i * 8] = r;
}

// ---------- kernel 2: T[(o1i1)*256+(o2i2)][r2] = sum_r1 c0*c1, bf16 out ----------
// thread computes 4 consecutive r2 via f4v c1 loads (4x fewer load instrs).
__global__ __launch_bounds__(256) void contract1b(const float* __restrict__ c0,
                                                  const float* __restrict__ c1,
                                                  unsigned short* __restrict__ T) {
  const int idx = blockIdx.x * 256 + threadIdx.x;   // 1,048,576
  const int r2q = idx & 15;                         // r2 = r2q*4 .. +3
  const int oi2 = (idx >> 4) & 255;
  const int oi1 = idx >> 12;                        // wave-uniform
  const float* c0p = c0 + oi1 * 64;
  const float* c1p = c1 + oi2 * 64 + r2q * 4;
  f4v s = (f4v)0.f;
#pragma unroll 8
  for (int r1 = 0; r1 < 64; ++r1) {
    const float t = c0p[r1];
    const f4v v = *(const f4v*)(c1p + r1 * 16384);
    s[0] = fmaf(t, v[0], s[0]); s[1] = fmaf(t, v[1], s[1]);
    s[2] = fmaf(t, v[2], s[2]); s[3] = fmaf(t, v[3], s[3]);
  }
  us4 o;
  o[0] = f2bf(s[0]); o[1] = f2bf(s[1]); o[2] = f2bf(s[2]); o[3] = f2bf(s[3]);
  *(us4*)&T[(size_t)idx * 4] = o;   // == (oi1*256+oi2)*64 + r2q*4
}

// ---------- kernel 2b: c2t[n=o3*16+i3][k=r2] bf16 = c2[r2][n] ----------
__global__ __launch_bounds__(256) void transc2(const float* __restrict__ c2,
                                               unsigned short* __restrict__ c2t) {
  const int n = blockIdx.x * 16 + (threadIdx.x >> 4);
  const int j = threadIdx.x & 15;                   // r2-quad
  us4 o;
#pragma unroll
  for (int q = 0; q < 4; ++q) o[q] = f2bf(c2[(j * 4 + q) * 256 + n]);
  *(us4*)&c2t[(size_t)n * 64 + j * 4] = o;
}

// ---------- kernel 3: buildW3 — 256x256x64 MFMA mini-GEMM per (o1,o2) ----------
// W[o1*256+o2*16+o3][i1*256+i2*16+i3] = sum_r2 T[(o1i1)(o2i2)][r2] * c2t[(o3i3)][r2]
// A = sT[m=(i1,i2)][k=r2], B = sC[n=(o3,i3)][k=r2]; same swizzle (slot ^= row&7)
// and D-layout (col=lane&15, row=(lane>>4)*4+r) as the verified main GEMM.
__global__ __launch_bounds__(256) void buildW3(const unsigned short* __restrict__ T,
                                               const unsigned short* __restrict__ c2t,
                                               unsigned short* __restrict__ W) {
  __shared__ unsigned short sT[16384];  // 32 KB [m 256][k 64] swizzled
  __shared__ unsigned short sC[16384];  // 32 KB [n 256][k 64] swizzled

  const int tid = threadIdx.x;
  const int o1 = blockIdx.x >> 4, o2 = blockIdx.x & 15;

  // stage (2048 us8 chunks each, 8/thread); swizzled LDS writes (reg-staged)
#pragma unroll
  for (int j = 0; j < 8; ++j) {
    const int c = j * 256 + tid;
    const int m = c >> 3, sl = c & 7;
    const int dst = m * 64 + ((sl ^ (m & 7)) << 3);
    *(us8*)&sT[dst] = *(const us8*)(T + (size_t)(o1 * 16 + (m >> 4)) * 16384 +
                                    (o2 * 16 + (m & 15)) * 64 + sl * 8);
    *(us8*)&sC[dst] = *(const us8*)(c2t + (size_t)m * 64 + sl * 8);
  }
  __syncthreads();

  const int lane = tid & 63, wid = tid >> 6;       // 4 waves, wave owns m-range wid*64
  const int fr = lane & 15, ks = lane >> 4;
  const int f7 = fr & 7;
  const int sx0 = ((ks ^ f7) << 3);                // kk=0 slot
  const int sx1 = (((4 + ks) ^ f7) << 3);          // kk=1 slot

  s8v a[4][2];
#pragma unroll
  for (int mi = 0; mi < 4; ++mi) {
    const unsigned short* p = &sT[(wid * 64 + mi * 16 + fr) * 64];
    a[mi][0] = *(const s8v*)(p + sx0);
    a[mi][1] = *(const s8v*)(p + sx1);
  }
#pragma unroll
  for (int nt = 0; nt < 16; ++nt) {
    const unsigned short* p = &sC[(nt * 16 + fr) * 64];
    const s8v b0 = *(const s8v*)(p + sx0);
    const s8v b1 = *(const s8v*)(p + sx1);
#pragma unroll
    for (int mi = 0; mi < 4; ++mi) {
      f4v acc = (f4v)0.f;
      acc = __builtin_amdgcn_mfma_f32_16x16x32_bf16(a[mi][0], b0, acc, 0, 0, 0);
      acc = __builtin_amdgcn_mfma_f32_16x16x32_bf16(a[mi][1], b1, acc, 0, 0, 0);
      // row_o = o1*256+o2*16+nt ; col_i = (wid*4+mi)*256 + (ks*4+r)*16 + fr
      unsigned short* wp = W + (size_t)(o1 * 256 + o2 * 16 + nt) * 4096 +
                           (wid * 4 + mi) * 256 + fr;
#pragma unroll
      for (int r = 0; r < 4; ++r) wp[(ks * 4 + r) * 16] = f2bf(acc[r]);
    }
  }
}

// ---------- kernel 4: 256x256-tile GEMM, m201-style 8-phase / 2 K-tiles per iter ----------
// Identical to R9 + m201's waitcnt choreography: lgkmcnt(8) before the barrier on
// 12-read phases (P1/P5), lgkmcnt(0) after every barrier before the MFMA cluster.

#define BAR() __builtin_amdgcn_s_barrier()
#define VMW(N) asm volatile("s_waitcnt vmcnt(" #N ")" ::: "memory")
#define LGK0() asm volatile("s_waitcnt lgkmcnt(0)")
#define LGK8() asm volatile("s_waitcnt lgkmcnt(8)")

template<int MQ, int NQ>
__device__ __forceinline__ void mmq(f4v (&acc)[8][4], const s8v (&a)[4][2], const s8v (&b)[2][2]) {
  __builtin_amdgcn_s_setprio(1);
#pragma unroll
  for (int mi = 0; mi < 4; ++mi)
#pragma unroll
    for (int ni = 0; ni < 2; ++ni)
#pragma unroll
      for (int q = 0; q < 2; ++q)
        acc[MQ * 4 + mi][NQ * 2 + ni] = __builtin_amdgcn_mfma_f32_16x16x32_bf16(
            a[mi][q], b[ni][q], acc[MQ * 4 + mi][NQ * 2 + ni], 0, 0, 0);
  __builtin_amdgcn_s_setprio(0);
}

__global__ __launch_bounds__(512, 2) void gemm8(const unsigned short* __restrict__ A,
                                                const unsigned short* __restrict__ B,
                                                float* __restrict__ C) {
  constexpr int M = 8192, N = 4096, K = 4096;
  constexpr int NT = K / 64;
  constexpr int NITER = NT / 2;
  constexpr int NXT = N / 256;

  __shared__ unsigned short lds[65536];   // 128 KiB

  const int tid  = threadIdx.x;
  const int lane = tid & 63;
  const int wid  = tid >> 6;
  const int wm   = wid >> 2;
  const int wn   = wid & 3;

  const int cpx = (int)gridDim.x >> 3;
  const int wg  = ((int)blockIdx.x & 7) * cpx + ((int)blockIdx.x >> 3);
  const long bm = (long)(wg / NXT) * 256;
  const long bn = (long)(wg % NXT) * 256;

  const int srow = tid >> 3;
  const int scol = ((tid & 7) ^ (srow & 7)) * 8;
  const unsigned short* gA = A + (bm + srow) * (size_t)K + scol;
  const unsigned short* gB = B + (bn + srow) * (size_t)K + scol;
  const size_t half64 = 64 * (size_t)K;
  const size_t k128   = 128 * (size_t)K;

#define STG(gp, koff, ldsU) do {                                  \
    const unsigned short* g_ = (gp) + (koff);                     \
    gll16(g_,          &lds[(ldsU) + tid * 8]);                   \
    gll16(g_ + half64, &lds[(ldsU) + 4096 + tid * 8]);            \
  } while (0)

  const int fr = lane & 15;
  const int ks = lane >> 4;
  const int f7 = fr & 7;
  const int sx0 = (ks ^ f7) * 8;
  const int sx1 = ((ks | 4) ^ f7) * 8;
  const int arow = (wm * 64 + fr) * 64;
  const int brow = (wn * 32 + fr) * 64;

#define RDA(MQ, bufU) do {                                                   \
    const unsigned short* p_ = &lds[(bufU) + (MQ) * 8192 + arow];            \
    a[0][0] = *(const s8v*)(p_ + sx0);        a[0][1] = *(const s8v*)(p_ + sx1); \
    a[1][0] = *(const s8v*)(p_ + 1024 + sx0); a[1][1] = *(const s8v*)(p_ + 1024 + sx1); \
    a[2][0] = *(const s8v*)(p_ + 2048 + sx0); a[2][1] = *(const s8v*)(p_ + 2048 + sx1); \
    a[3][0] = *(const s8v*)(p_ + 3072 + sx0); a[3][1] = *(const s8v*)(p_ + 3072 + sx1); \
  } while (0)
#define RDB(dst, NQ, bufU) do {                                              \
    const unsigned short* p_ = &lds[(bufU) + 16384 + (NQ) * 8192 + brow];    \
    dst[0][0] = *(const s8v*)(p_ + sx0);        dst[0][1] = *(const s8v*)(p_ + sx1); \
    dst[1][0] = *(const s8v*)(p_ + 1024 + sx0); dst[1][1] = *(const s8v*)(p_ + 1024 + sx1); \
  } while (0)

  f4v acc[8][4];
#pragma unroll
  for (int m = 0; m < 8; ++m)
#pragma unroll
    for (int n = 0; n < 4; ++n) acc[m][n] = (f4v)0.0f;

  STG(gA,        0, 0);
  STG(gA + k128, 0, 8192);
  STG(gB,        0, 16384);
  STG(gB + k128, 0, 24576);
  STG(gA,        64, 32768);
  STG(gB + k128, 64, 32768 + 24576);
  VMW(4);
  BAR();

  s8v a[4][2], b0[2][2], b1[2][2];

  for (int i = 0; i < NITER; ++i) {
    const long w = (i == NITER - 1) ? -4096L : 0L;
    // ---- P1 (12 reads): Q(0,0) c0; stage A-hi(c1) ----
    RDA(0, 0); RDB(b0, 0, 0);
    STG(gA + k128, 64, 32768 + 8192);
    LGK8();
    BAR(); LGK0(); mmq<0, 0>(acc, a, b0); BAR();
    // ---- P2: Q(0,1); stage B-lo(c1) ----
    RDB(b1, 1, 0);
    STG(gB, 64, 32768 + 16384);
    BAR(); LGK0(); mmq<0, 1>(acc, a, b1); BAR();
    // ---- P3: Q(1,1); stage A-lo(c0+2) ----
    RDA(1, 0);
    STG(gA, 128 + w, 0);
    BAR(); LGK0(); mmq<1, 1>(acc, a, b1); BAR();
    // ---- P4: Q(1,0); stage B-hi(c0+2); VMW lands ALL of c1 ----
    STG(gB + k128, 128 + w, 24576);
    BAR(); mmq<1, 0>(acc, a, b0);
    VMW(4); BAR();
    // ---- P5 (12 reads): Q(0,0) c1; stage A-hi(c0+2) ----
    RDA(0, 32768); RDB(b0, 0, 32768);
    STG(gA + k128, 128 + w, 8192);
    LGK8();
    BAR(); LGK0(); mmq<0, 0>(acc, a, b0); BAR();
    // ---- P6: Q(0,1); stage B-lo(c0+2) ----
    RDB(b1, 1, 32768);
    STG(gB, 128 + w, 16384);
    BAR(); LGK0(); mmq<0, 1>(acc, a, b1); BAR();
    // ---- P7: Q(1,1); stage A-lo(c1+2) ----
    RDA(1, 32768);
    STG(gA, 192 + w, 32768);
    BAR(); LGK0(); mmq<1, 1>(acc, a, b1); BAR();
    // ---- P8: Q(1,0); stage B-hi(c1+2); VMW lands ALL of c0+2 ----
    STG(gB + k128, 192 + w, 32768 + 24576);
    BAR(); mmq<1, 0>(acc, a, b0);
    VMW(4); BAR();

    gA += 128; gB += 128;
  }
  VMW(0);

#pragma unroll
  for (int mq = 0; mq < 2; ++mq)
#pragma unroll
    for (int mi = 0; mi < 4; ++mi)
#pragma unroll
      for (int nq = 0; nq < 2; ++nq)
#pragma unroll
        for (int ni = 0; ni < 2; ++ni) {
          const size_t row0 = bm + mq * 128 + wm * 64 + mi * 16 + ks * 4;
          const size_t col  = bn + nq * 128 + wn * 32 + ni * 16 + fr;
          float* cp = C + row0 * (size_t)N + col;
          f4v v = acc[mq * 4 + mi][nq * 2 + ni];
          cp[0] = v[0]; cp[N] = v[1]; cp[2 * (size_t)N] = v[2]; cp[3 * (size_t)N] = v[3];
        }
#undef STG
#undef RDA
#undef RDB
}

// ---------- launch ----------
extern "C" void kernel_launch(void* const* d_in, const int* in_sizes, int n_in,
                              void* d_out, int out_size, void* d_ws, size_t ws_size,
                              hipStream_t stream) {
  const float* x  = (const float*)d_in[0];   // [8192,4096]
  const float* c0 = (const float*)d_in[1];   // [1,16,16,64]
  const float* c1 = (const float*)d_in[2];   // [64,16,16,64]
  const float* c2 = (const float*)d_in[3];   // [64,16,16,1]
  float* out = (float*)d_out;                // [8192,4096] fp32

  char* ws = (char*)d_ws;
  unsigned short* T   = (unsigned short*)ws;                      // 8 MB  bf16 [(o1i1)(o2i2)][r2]
  unsigned short* c2t = (unsigned short*)(ws + (8u << 20));       // 32 KB bf16 [n][r2]
  unsigned short* Wb  = (unsigned short*)(ws + (16u << 20));      // 32 MB bf16 [out][in]
  unsigned short* xb  = (unsigned short*)(ws + (48u << 20));      // 64 MB bf16 [8192][4096]

  hipLaunchKernelGGL(cast_bf16,  dim3(16384), dim3(256), 0, stream, x, xb);
  hipLaunchKernelGGL(contract1b, dim3(4096),  dim3(256), 0, stream, c0, c1, T);
  hipLaunchKernelGGL(transc2,    dim3(16),    dim3(256), 0, stream, c2, c2t);
  hipLaunchKernelGGL(buildW3,    dim3(256),   dim3(256), 0, stream, T, c2t, Wb);
  hipLaunchKernelGGL(gemm8,      dim3(512),   dim3(512), 0, stream, xb, Wb, out);
}